// Round 1
// baseline (236.276 us; speedup 1.0000x reference)
//
#include <hip/hip_runtime.h>

// SplineFilter: out[b,n,f] = eval_x[b,n,f] * sf^2,
//   sf = sum_k basis_k(eigs[b,n]) * coeffs[k,f]
// basis = cubic B-spline (Cox-de Boor) over knots = linspace(0,2,16) -> 12 bases.
//
// Memory-bound: ~269 MB HBM traffic/launch. One thread per float4 output.
// 32 threads per (b,n) row (128 features / 4). Coeffs (6 KB) staged in LDS.

#define N_BASES 12
#define F_CH 128

__device__ __forceinline__ constexpr float kn(int i) {
    // jnp.linspace(0, 2, 16) -> step = 2/15
    return (float)i * (2.0f / 15.0f);
}

__global__ __launch_bounds__(256) void spline_filter_kernel(
    const float4* __restrict__ x4,      // eval_x as float4, [rows*32]
    const float*  __restrict__ eigs,    // [rows]
    const float4* __restrict__ coeffs4, // [12*32] (12 x 128 floats)
    float4*       __restrict__ out4,    // [rows*32]
    int n_rows)
{
    __shared__ float4 sc[N_BASES * (F_CH / 4)];  // 12*32 float4 = 6 KB

    const int t = threadIdx.x;
    // Stage coeffs into LDS (384 float4 with 256 threads -> 2 iters)
    #pragma unroll
    for (int i = t; i < N_BASES * (F_CH / 4); i += 256) {
        sc[i] = coeffs4[i];
    }
    __syncthreads();

    const int gid  = blockIdx.x * 256 + t;
    const int row  = gid >> 5;        // which (b,n)
    const int lane = gid & 31;        // which float4 within the 128 features
    if (row >= n_rows) return;

    const float x = eigs[row];

    // ---- Cox-de Boor, degree 3, uniform knots (all denominators > 0) ----
    float bb[15];
    #pragma unroll
    for (int i = 0; i < 15; ++i) {
        bb[i] = (x >= kn(i) && x < kn(i + 1)) ? 1.0f : 0.0f;
    }
    #pragma unroll
    for (int d = 1; d <= 3; ++d) {
        #pragma unroll
        for (int i = 0; i + d < 15; ++i) {
            const float linv = 1.0f / (kn(i + d) - kn(i));         // folds to literal
            const float rinv = 1.0f / (kn(i + d + 1) - kn(i + 1)); // folds to literal
            const float left  = (x - kn(i)) * linv;
            const float right = (kn(i + d + 1) - x) * rinv;
            bb[i] = left * bb[i] + right * bb[i + 1];
        }
    }
    // bb[0..11] now hold the 12 cubic basis values.

    // ---- spectral filter for this thread's 4 features ----
    float4 sf = make_float4(0.f, 0.f, 0.f, 0.f);
    #pragma unroll
    for (int k = 0; k < N_BASES; ++k) {
        const float4 c = sc[k * (F_CH / 4) + lane];
        sf.x += bb[k] * c.x;
        sf.y += bb[k] * c.y;
        sf.z += bb[k] * c.z;
        sf.w += bb[k] * c.w;
    }

    const float4 xv = x4[gid];
    float4 o;
    o.x = xv.x * sf.x * sf.x;
    o.y = xv.y * sf.y * sf.y;
    o.z = xv.z * sf.z * sf.z;
    o.w = xv.w * sf.w * sf.w;
    out4[gid] = o;
}

extern "C" void kernel_launch(void* const* d_in, const int* in_sizes, int n_in,
                              void* d_out, int out_size, void* d_ws, size_t ws_size,
                              hipStream_t stream) {
    const float* eval_x  = (const float*)d_in[0];  // [32,8192,128] fp32
    const float* eigs    = (const float*)d_in[1];  // [32,8192]     fp32
    const float* coeffs  = (const float*)d_in[2];  // [12,128]      fp32
    float* out = (float*)d_out;

    const int n_rows = in_sizes[1];          // 32*8192 = 262144
    const int total4 = in_sizes[0] / 4;      // 8388608 float4 elements
    const int blocks = (total4 + 255) / 256; // 32768

    spline_filter_kernel<<<blocks, 256, 0, stream>>>(
        (const float4*)eval_x, eigs, (const float4*)coeffs, (float4*)out, n_rows);
}

// Round 2
// 226.100 us; speedup vs baseline: 1.0450x; 1.0450x over previous
//
#include <hip/hip_runtime.h>

// SplineFilter: out[b,n,f] = eval_x[b,n,f] * sf^2,
//   sf = sum_k basis_k(eigs[b,n]) * coeffs[k,f]
// Cubic B-spline over uniform knots linspace(0,2,16), 12 bases.
//
// Key optimization vs round 1: only 4 of the 12 cubic bases are nonzero for
// any x (support = 4 intervals). With uniform knots (h = 2/15) the nonzero
// weights are the cardinal cubic B-spline polynomials in t = x/h - i:
//   k=i-3: (1-t)^3/6
//   k=i-2: (3t^3 - 6t^2 + 4)/6
//   k=i-1: (-3t^3 + 3t^2 + 3t + 1)/6
//   k=i  : t^3/6
// (verified against Cox-de Boor on the open uniform knot vector).
// Per-thread VALU drops ~210 -> ~35 ops; kernel flips to memory-bound.

#define N_BASES 12
#define F_CH 128

__global__ __launch_bounds__(256) void spline_filter_kernel(
    const float4* __restrict__ x4,      // eval_x as float4, [rows*32]
    const float*  __restrict__ eigs,    // [rows]
    const float4* __restrict__ coeffs4, // [12*32] (12 x 128 floats)
    float4*       __restrict__ out4,    // [rows*32]
    int n_rows)
{
    __shared__ float4 sc[N_BASES * (F_CH / 4)];  // 12*32 float4 = 6 KB

    const int t = threadIdx.x;
    #pragma unroll
    for (int i = t; i < N_BASES * (F_CH / 4); i += 256) {
        sc[i] = coeffs4[i];
    }
    __syncthreads();

    const int gid  = blockIdx.x * 256 + t;
    const int row  = gid >> 5;        // which (b,n)
    const int lane = gid & 31;        // which float4 within the 128 features
    if (row >= n_rows) return;

    const float x = eigs[row];

    // ---- 4 nonzero cardinal cubic weights ----
    const float u  = x * 7.5f;            // x / (2/15)
    const int   i  = (int)floorf(u);      // interval index (x>=0)
    const float tt = u - (float)i;
    const float t2 = tt * tt;
    const float t3 = t2 * tt;
    const float omt = 1.0f - tt;
    float w[4];
    w[0] = omt * omt * omt * (1.0f / 6.0f);               // k = i-3
    w[1] = (3.0f * t3 - 6.0f * t2 + 4.0f) * (1.0f / 6.0f); // k = i-2
    w[2] = (-3.0f * t3 + 3.0f * t2 + 3.0f * tt + 1.0f) * (1.0f / 6.0f); // k = i-1
    w[3] = t3 * (1.0f / 6.0f);                             // k = i

    // ---- spectral filter for this thread's 4 features (branchless edges) ----
    float4 sf = make_float4(0.f, 0.f, 0.f, 0.f);
    #pragma unroll
    for (int j = 0; j < 4; ++j) {
        const int k   = i - 3 + j;
        const int kc  = min(max(k, 0), N_BASES - 1);
        const float wj = (k == kc) ? w[j] : 0.0f;  // zero weight if clamped
        const float4 c = sc[kc * (F_CH / 4) + lane];
        sf.x += wj * c.x;
        sf.y += wj * c.y;
        sf.z += wj * c.z;
        sf.w += wj * c.w;
    }

    const float4 xv = x4[gid];
    float4 o;
    o.x = xv.x * sf.x * sf.x;
    o.y = xv.y * sf.y * sf.y;
    o.z = xv.z * sf.z * sf.z;
    o.w = xv.w * sf.w * sf.w;
    out4[gid] = o;
}

extern "C" void kernel_launch(void* const* d_in, const int* in_sizes, int n_in,
                              void* d_out, int out_size, void* d_ws, size_t ws_size,
                              hipStream_t stream) {
    const float* eval_x  = (const float*)d_in[0];  // [32,8192,128] fp32
    const float* eigs    = (const float*)d_in[1];  // [32,8192]     fp32
    const float* coeffs  = (const float*)d_in[2];  // [12,128]      fp32
    float* out = (float*)d_out;

    const int n_rows = in_sizes[1];          // 32*8192 = 262144
    const int total4 = in_sizes[0] / 4;      // 8388608 float4 elements
    const int blocks = (total4 + 255) / 256; // 32768

    spline_filter_kernel<<<blocks, 256, 0, stream>>>(
        (const float4*)eval_x, eigs, (const float4*)coeffs, (float4*)out, n_rows);
}

// Round 4
// 224.725 us; speedup vs baseline: 1.0514x; 1.0061x over previous
//
#include <hip/hip_runtime.h>

// SplineFilter: out[b,n,f] = eval_x[b,n,f] * sf^2,
//   sf = sum_k basis_k(eigs[b,n]) * coeffs[k,f]
// Cubic B-spline over uniform knots linspace(0,2,16), 12 bases; only 4
// nonzero per x (cardinal cubic weights in t = x/h - i).
//
// Memory-bound kernel -> maximize MLP:
// - Each thread handles CHUNKS=4 grid-strided float4 outputs; all global
//   loads (x4 + eigs) issued up front -> 4 KB outstanding per wave.
// - 8192 blocks instead of 32768 -> 4x less LDS-staging overhead.
// - Non-temporal load/store on the streamed arrays (no reuse).
//   NOTE: __builtin_nontemporal_* requires a clang ext_vector_type, not
//   HIP_vector_type (float4) -- use vf4 below.

#define N_BASES 12
#define F_CH 128
#define CHUNKS 4

typedef float vf4 __attribute__((ext_vector_type(4)));

__global__ __launch_bounds__(256) void spline_filter_kernel(
    const vf4* __restrict__ x4,      // eval_x as vf4
    const float* __restrict__ eigs,  // [rows]
    const vf4* __restrict__ coeffs4, // [12*32]
    vf4*       __restrict__ out4,
    int total4, int stride4)
{
    __shared__ vf4 sc[N_BASES * (F_CH / 4)];  // 6 KB

    const int t = threadIdx.x;
    #pragma unroll
    for (int i = t; i < N_BASES * (F_CH / 4); i += 256) {
        sc[i] = coeffs4[i];
    }
    __syncthreads();

    const int gid = blockIdx.x * 256 + t;

    int idx[CHUNKS];
    vf4 xv [CHUNKS];
    float eg[CHUNKS];

    // Issue all global loads up front (4x MLP).
    #pragma unroll
    for (int c = 0; c < CHUNKS; ++c) {
        idx[c] = gid + c * stride4;
        if (idx[c] < total4) {
            xv[c] = __builtin_nontemporal_load(&x4[idx[c]]);
            eg[c] = eigs[idx[c] >> 5];
        } else {
            xv[c] = (vf4)0.0f;
            eg[c] = 0.f;
        }
    }

    #pragma unroll
    for (int c = 0; c < CHUNKS; ++c) {
        if (idx[c] >= total4) continue;
        const int lane = idx[c] & 31;

        // 4 nonzero cardinal cubic weights for x = eg[c]
        const float x  = eg[c];
        const float u  = x * 7.5f;            // x / (2/15)
        const int   i  = (int)floorf(u);
        const float tt = u - (float)i;
        const float t2 = tt * tt;
        const float t3 = t2 * tt;
        const float omt = 1.0f - tt;
        float w[4];
        w[0] = omt * omt * omt * (1.0f / 6.0f);                             // k=i-3
        w[1] = (3.0f * t3 - 6.0f * t2 + 4.0f) * (1.0f / 6.0f);              // k=i-2
        w[2] = (-3.0f * t3 + 3.0f * t2 + 3.0f * tt + 1.0f) * (1.0f / 6.0f); // k=i-1
        w[3] = t3 * (1.0f / 6.0f);                                          // k=i

        vf4 sf = (vf4)0.0f;
        #pragma unroll
        for (int j = 0; j < 4; ++j) {
            const int k  = i - 3 + j;
            const int kc = min(max(k, 0), N_BASES - 1);
            const float wj = (k == kc) ? w[j] : 0.0f;  // zero if clamped
            sf += wj * sc[kc * (F_CH / 4) + lane];
        }

        const vf4 o = xv[c] * sf * sf;
        __builtin_nontemporal_store(o, &out4[idx[c]]);
    }
}

extern "C" void kernel_launch(void* const* d_in, const int* in_sizes, int n_in,
                              void* d_out, int out_size, void* d_ws, size_t ws_size,
                              hipStream_t stream) {
    const float* eval_x  = (const float*)d_in[0];  // [32,8192,128] fp32
    const float* eigs    = (const float*)d_in[1];  // [32,8192]     fp32
    const float* coeffs  = (const float*)d_in[2];  // [12,128]      fp32
    float* out = (float*)d_out;

    const int total4 = in_sizes[0] / 4;                               // 8388608
    const int blocks = (total4 + 256 * CHUNKS - 1) / (256 * CHUNKS);  // 8192
    const int stride4 = blocks * 256;

    spline_filter_kernel<<<blocks, 256, 0, stream>>>(
        (const vf4*)eval_x, eigs, (const vf4*)coeffs, (vf4*)out,
        total4, stride4);
}